// Round 7
// baseline (2324.029 us; speedup 1.0000x reference)
//
#include <hip/hip_runtime.h>
#include <hip/hip_bf16.h>

typedef __hip_bfloat16 bf16;
typedef __attribute__((ext_vector_type(8))) short bf16x8;
typedef __attribute__((ext_vector_type(4))) float f32x4;

#define HH 300     // hidden
#define NMOLS 2000
#define AFD 133    // atom feature dim
#define BFD 147    // bond feature dim
#define KP 480     // padded K of WT buffers (15 steps of 32)
#define GOFS 160   // tail region starts at k=160 (step 5)
#define NWT (320 * KP)   // elements per WT buffer

// ---- build WT[c][k] bf16: k<fd -> W0[k][c]; 160<=k<460 -> W1[k-160][c]; else 0 ----
// Zero pad cols are load-bearing: GEMM A-tail reads up to 20 bf16 past row end
// (next row's data / region tail) and relies on WT==0 at k>=460 (MODE2: >=444).
__global__ void build_wt(const float* __restrict__ W0, const float* __restrict__ W1,
                         int fd, bf16* __restrict__ WT)
{
  int idx = blockIdx.x * 256 + threadIdx.x;
  if (idx >= NWT) return;
  int c = idx / KP, k = idx - c * KP;
  float v = 0.f;
  if (c < HH) {
    if (k < fd) v = W0[(size_t)k * HH + c];
    else if (k >= GOFS && k < GOFS + HH) v = W1[(size_t)(k - GOFS) * HH + c];
  }
  WT[idx] = __float2bfloat16(v);
}

// ---- amsg[a][k] = sum_j msg[a2b[a][j]][k], bf16; thread = 4 elems (8B loads) ----
__global__ __launch_bounds__(256)
void gather6_k(const bf16* __restrict__ msg, const int* __restrict__ a2b,
               bf16* __restrict__ amsg, int A)
{
  int idx = blockIdx.x * 256 + threadIdx.x;
  if (idx >= A * 75) return;
  int a = idx / 75;
  int k4 = (idx - a * 75) * 4;
  const int* p = a2b + (size_t)a * 6;
  float s[4] = {0.f, 0.f, 0.f, 0.f};
#pragma unroll
  for (int j = 0; j < 6; j++) {
    uint2 u = *(const uint2*)(msg + (size_t)p[j] * HH + k4);
    union { unsigned u; float f; } c;
    c.u = u.x << 16;         s[0] += c.f;
    c.u = u.x & 0xffff0000u; s[1] += c.f;
    c.u = u.y << 16;         s[2] += c.f;
    c.u = u.y & 0xffff0000u; s[3] += c.f;
  }
  bf16 t[4];
#pragma unroll
  for (int j = 0; j < 4; j++) t[j] = __float2bfloat16(s[j]);
  *(uint2*)(amsg + (size_t)a * HH + k4) = *(const uint2*)t;
}

// ---- t[r][k] = amsg[b2a[r]][k] - msg[b2revb[r]][k], bf16; thread = 4 elems ----
// Barrier-free streaming gather at max occupancy: the random-row latency is
// hidden by thousands of independent waves, unlike inside the GEMM.
__global__ __launch_bounds__(256)
void update_k(const bf16* __restrict__ amsg, const bf16* __restrict__ msg,
              const int* __restrict__ b2a, const int* __restrict__ b2revb,
              bf16* __restrict__ t, int B)
{
  int idx = blockIdx.x * 256 + threadIdx.x;
  if (idx >= B * 75) return;
  int r = idx / 75;
  int k4 = (idx - r * 75) * 4;
  int aa = b2a[r], rb = b2revb[r];
  uint2 ua = *(const uint2*)(amsg + (size_t)aa * HH + k4);
  uint2 ub = *(const uint2*)(msg + (size_t)rb * HH + k4);
  unsigned wa[2] = {ua.x, ua.y}, wb[2] = {ub.x, ub.y};
  bf16 o[4];
#pragma unroll
  for (int q = 0; q < 2; q++) {
    union { unsigned u; float f; } alo, ahi, blo, bhi;
    alo.u = wa[q] << 16;         blo.u = wb[q] << 16;
    ahi.u = wa[q] & 0xffff0000u; bhi.u = wb[q] & 0xffff0000u;
    o[2 * q]     = __float2bfloat16(alo.f - blo.f);
    o[2 * q + 1] = __float2bfloat16(ahi.f - bhi.f);
  }
  *(uint2*)(t + (size_t)r * HH + k4) = *(const uint2*)o;
}

// ============ fully-DENSE pipelined MFMA GEMM: 64 rows x 320 cols, 4 waves ============
// K layout: steps 0..4 = features (A0 f32, k<FD), steps 5..14 = tail bf16 rows
// (sequential read of tail[arow*300 + kk]).
// MODE 0: C = f_bonds @ W_i (5 steps);      msg_out = relu(C), row0=0
// MODE 1: C = f_bonds@W_i + t@W_h;          msg_out = relu(C), row0=0  (in-place OK)
// MODE 2: C = [f_atoms | amsg] @ W_o;       hid = relu(C + bias)
template<int MODE>
__global__ __launch_bounds__(256)
void gemm_d(const float* __restrict__ A0, const bf16* __restrict__ WT,
            const bf16* __restrict__ tail, const float* __restrict__ bias,
            bf16* __restrict__ msg_out, float* __restrict__ hid_out, int M)
{
  constexpr int KSTEPS = (MODE == 0) ? 5 : 15;
  constexpr int FD = (MODE == 2) ? AFD : BFD;

  __shared__ __align__(16) short As[4][64 * 32];   // 4-deep ring, 4KB each

  const int tid = threadIdx.x;
  const int lane = tid & 63;
  const int wave = tid >> 6;
  const int gm0 = blockIdx.x * 64;

  // staging role: 4 threads per row, 8 bf16 (16B) per thread per step
  const int sr = tid >> 2;
  const int ss = tid & 3;
  const int arow = gm0 + sr;
  const bool rok = arow < M;
  const int stoff = sr * 32 + (((ss ^ (sr >> 1)) & 3)) * 8;  // XOR-swizzled slot
  const char* trow = (const char*)tail + (size_t)(rok ? arow : 0) * (HH * 2);

  // compute role: A-frag LDS offsets (4 row tiles), B global base
  const int crow = lane & 15;
  const int kq = lane >> 4;
  int aoff[4];
#pragma unroll
  for (int i = 0; i < 4; i++) {
    int r = i * 16 + crow;
    aoff[i] = r * 32 + ((kq ^ (r >> 1)) & 3) * 8;
  }
  const bf16* bbase = WT + (size_t)(wave * 80 + crow) * KP + kq * 8;

  f32x4 acc[4][5];
#pragma unroll
  for (int i = 0; i < 4; i++)
#pragma unroll
    for (int j = 0; j < 5; j++) acc[i][j] = (f32x4){0.f, 0.f, 0.f, 0.f};

  // 3 in-flight register sets (prefetch distance 3)
  float fv[3][8];
  uint2 ga[3][2];

  auto issue = [&](int s) {
    const int set = s % 3;
    if (s < 5) {
      int kb = s * 32 + ss * 8;
#pragma unroll
      for (int j = 0; j < 8; j++) {
        int k = kb + j;
        fv[set][j] = (rok && k < FD) ? A0[(size_t)arow * FD + k] : 0.f;
      }
    } else {
      // sequential tail read; may run past row end into next row / region pad --
      // harmless: WT is zero for those k. Stays within the ws region (checked).
      int kk = (s - 5) * 32 + ss * 8;
      const char* pa = trow + (size_t)kk * 2;
      ga[set][0] = *(const uint2*)pa;
      ga[set][1] = *(const uint2*)(pa + 8);
    }
  };

  auto finish = [&](int s) {
    const int set = s % 3;
    short* dst = &As[s & 3][stoff];
    if (s < 5) {
      bf16x8 t;
#pragma unroll
      for (int j = 0; j < 8; j++) {
        union { bf16 b; short sh; } cv; cv.b = __float2bfloat16(fv[set][j]); t[j] = cv.sh;
      }
      *(bf16x8*)dst = t;
    } else {
      *(uint2*)dst = ga[set][0];
      *(uint2*)(dst + 4) = ga[set][1];
    }
  };

  // ---- prologue: fill pipeline (depth 3), stage step 0 ----
  issue(0); issue(1); issue(2);
  finish(0);
  asm volatile("s_waitcnt lgkmcnt(0)" ::: "memory");
  __builtin_amdgcn_s_barrier();

  // ---- main loop: one raw barrier per step, prefetched loads in flight across it ----
#pragma unroll
  for (int s = 0; s < KSTEPS; s++) {
    if (s + 3 < KSTEPS) issue(s + 3);

    {
      const short* curb = &As[s & 3][0];
      bf16x8 af[4], bfr[5];
#pragma unroll
      for (int i = 0; i < 4; i++) af[i] = *(const bf16x8*)(curb + aoff[i]);
      const bf16* bb = bbase + s * 32;
#pragma unroll
      for (int j = 0; j < 5; j++) bfr[j] = *(const bf16x8*)(bb + (size_t)j * 16 * KP);
#pragma unroll
      for (int j = 0; j < 5; j++)
#pragma unroll
        for (int i = 0; i < 4; i++)
          acc[i][j] = __builtin_amdgcn_mfma_f32_16x16x32_bf16(af[i], bfr[j], acc[i][j], 0, 0, 0);
    }

    if (s + 1 < KSTEPS) {
      finish(s + 1);
      asm volatile("s_waitcnt lgkmcnt(0)" ::: "memory");
      __builtin_amdgcn_s_barrier();
    }
  }

  // ---- epilogue: C/D frag col=lane&15, row=(lane>>4)*4+reg ----
#pragma unroll
  for (int j = 0; j < 5; j++) {
    int c = wave * 80 + j * 16 + crow;
    if (c >= HH) continue;
    float bia = (MODE == 2) ? bias[c] : 0.f;
#pragma unroll
    for (int i = 0; i < 4; i++) {
#pragma unroll
      for (int r = 0; r < 4; r++) {
        int g = gm0 + i * 16 + kq * 4 + r;
        if (g >= M) continue;
        float v = acc[i][j][r];
        if (MODE == 2) {
          hid_out[(size_t)g * HH + c] = fmaxf(v + bia, 0.f);
        } else {
          float rv = fmaxf(v, 0.f);
          if (g == 0) rv = 0.f;
          msg_out[(size_t)g * HH + c] = __float2bfloat16(rv);
        }
      }
    }
  }
}

// per-molecule mean over sorted mol_id (binary search, no atomics)
__global__ void readout_k(const float* __restrict__ hid, const int* __restrict__ mol_id,
                          float* __restrict__ out, int A)
{
  __shared__ int bnd[2];
  int m = blockIdx.x;
  if (threadIdx.x < 2) {
    int target = m + (int)threadIdx.x;
    int lo = 0, hi = A;
    while (lo < hi) { int mid = (lo + hi) >> 1; if (mol_id[mid] < target) lo = mid + 1; else hi = mid; }
    bnd[threadIdx.x] = lo;
  }
  __syncthreads();
  int s = bnd[0], e = bnd[1];
  int h = threadIdx.x;
  if (h >= HH) return;
  float acc = 0.f;
  for (int a = s; a < e; a++) acc += hid[(size_t)a * HH + h];
  int cnt = e - s; if (cnt < 1) cnt = 1;
  out[(size_t)m * HH + h] = acc / (float)cnt;
}

extern "C" void kernel_launch(void* const* d_in, const int* in_sizes, int n_in,
                              void* d_out, int out_size, void* d_ws, size_t ws_size,
                              hipStream_t stream)
{
  const float* f_atoms[2] = {(const float*)d_in[0], (const float*)d_in[2]};
  const float* f_bonds[2] = {(const float*)d_in[1], (const float*)d_in[3]};
  const float* W_i[2]     = {(const float*)d_in[4], (const float*)d_in[5]};
  const float* W_h[2]     = {(const float*)d_in[6], (const float*)d_in[7]};
  const float* W_o[2]     = {(const float*)d_in[8], (const float*)d_in[10]};
  const float* b_o[2]     = {(const float*)d_in[9], (const float*)d_in[11]};
  const int* a2b[2]    = {(const int*)d_in[12], (const int*)d_in[16]};
  const int* b2a[2]    = {(const int*)d_in[13], (const int*)d_in[17]};
  const int* b2revb[2] = {(const int*)d_in[14], (const int*)d_in[18]};
  const int* mol_id[2] = {(const int*)d_in[15], (const int*)d_in[19]};
  const int A = in_sizes[0] / AFD;   // 100001
  const int B = in_sizes[1] / BFD;   // 200001

  // ws: M0 bf16[B,H] | M1 bf16[B,H] / hid f32[A,H] overlay | amsg bf16[A,H] | 4x WT
  auto al = [](size_t x){ return (x + 255) & ~(size_t)255; };
  size_t r0 = al((size_t)B * HH * sizeof(bf16));
  size_t r1sz = (size_t)B * HH * sizeof(bf16);
  size_t hsz  = (size_t)A * HH * sizeof(float);
  size_t r1 = al(r1sz > hsz ? r1sz : hsz);
  size_t amsz = al((size_t)A * HH * sizeof(bf16));
  size_t wtsz = al((size_t)NWT * sizeof(bf16));
  if (ws_size < r0 + r1 + amsz + 4 * wtsz) return;  // proven available in round 5

  char* ws = (char*)d_ws;
  bf16*  M0  = (bf16*)ws;
  bf16*  M1  = (bf16*)(ws + r0);
  float* hid = (float*)(ws + r0);
  bf16*  amsg = (bf16*)(ws + r0 + r1);
  size_t wofs = r0 + r1 + amsz;
  bf16* WT1[2] = {(bf16*)(ws + wofs),            (bf16*)(ws + wofs + wtsz)};
  bf16* WT2[2] = {(bf16*)(ws + wofs + 2 * wtsz), (bf16*)(ws + wofs + 3 * wtsz)};

  dim3 blk(256);
  dim3 gW((NWT + 255) / 256);
  dim3 gB((B + 63) / 64);
  dim3 gA((A + 63) / 64);
  dim3 gG((A * 75 + 255) / 256);
  dim3 gU((B * 75 + 255) / 256);

  for (int p = 0; p < 2; p++) {
    build_wt<<<gW, blk, 0, stream>>>(W_i[p], W_h[p], BFD, WT1[p]);
    build_wt<<<gW, blk, 0, stream>>>(W_o[p], W_o[p] + (size_t)AFD * HH, AFD, WT2[p]);
  }

  for (int p = 0; p < 2; p++) {
    float* out_p = (float*)d_out + (size_t)p * NMOLS * HH;
    // msg(M0) = relu(f_bonds @ W_i), row0=0
    gemm_d<0><<<gB, blk, 0, stream>>>(f_bonds[p], WT1[p], nullptr, nullptr,
                                      M0, nullptr, B);
    // iteration 1: amsg = gather6(M0); t(M1) = amsg[b2a]-M0[b2revb]; M1 = relu(fb@Wi + t@Wh)
    gather6_k<<<gG, blk, 0, stream>>>(M0, a2b[p], amsg, A);
    update_k <<<gU, blk, 0, stream>>>(amsg, M0, b2a[p], b2revb[p], M1, B);
    gemm_d<1><<<gB, blk, 0, stream>>>(f_bonds[p], WT1[p], M1, nullptr,
                                      M1, nullptr, B);   // in-place
    // iteration 2
    gather6_k<<<gG, blk, 0, stream>>>(M1, a2b[p], amsg, A);
    update_k <<<gU, blk, 0, stream>>>(amsg, M1, b2a[p], b2revb[p], M0, B);
    gemm_d<1><<<gB, blk, 0, stream>>>(f_bonds[p], WT1[p], M0, nullptr,
                                      M0, nullptr, B);   // in-place
    // output layer
    gather6_k<<<gG, blk, 0, stream>>>(M0, a2b[p], amsg, A);
    gemm_d<2><<<gA, blk, 0, stream>>>(f_atoms[p], WT2[p], amsg, b_o[p],
                                      nullptr, hid, A);
    // per-molecule mean readout
    readout_k<<<NMOLS, 320, 0, stream>>>(hid, mol_id[p], out_p, A);
  }
}